// Round 3
// baseline (76.050 us; speedup 1.0000x reference)
//
#include <hip/hip_runtime.h>
#include <math.h>

// PairwiseRankingLoss: B=64, N=1024, margin=1.0 — single fused kernel.
//   valid = ~isnan(targets); pairs (i,j), i!=j, both valid
//   loss_ij = relu(1 - (p_i - p_j)) if t_i > t_j else relu(1 + (p_i - p_j))
//           = relu(1 + s*(p_i - p_j)),  s = -1 if t_i > t_j else +1
//           = relu(1 + ((p_i - p_j) XOR signbit(t_j - t_i)))   [branch-free]
// Invalid j staged as (t,p) = (-inf,-inf): for valid i, d = p_i-(-inf) = +inf,
// dt = -inf -> sign=1 -> sd = -inf -> relu(1-inf) = 0. Invalid rows masked at end.
// Computed in packed f16 (v_pk_*): 28 insts / 8 pairs; f32 accumulation per row.

#define BN 1024
#define NB 64
#define NPART 16  // j-partitions per sample (64 j's each)
#define JP 64

typedef _Float16 h8v __attribute__((ext_vector_type(8)));
typedef unsigned int u32x4 __attribute__((ext_vector_type(4)));

__device__ float g_loss[NB];   // per-sample pair-loss sums   (reset by last block)
__device__ int   g_cnt[NB];    // per-sample valid counts     (reset by last block)
__device__ int   g_done;       // completed-block counter     (reset by last block)

__global__ __launch_bounds__(256) void prl_fused(const float* __restrict__ P,
                                                 const float* __restrict__ T,
                                                 float* __restrict__ out) {
    const int blk = blockIdx.x;
    const int b   = blk >> 4;   // sample
    const int q   = blk & 15;   // j-partition
    const int tid = threadIdx.x;

    __shared__ __align__(16) _Float16 sp[JP];
    __shared__ __align__(16) _Float16 st[JP];
    __shared__ float wsum[4];
    __shared__ int   s_last;

    if (tid < JP) {             // one wave stages + counts valids
        float t = T[b * BN + q * JP + tid];
        float p = P[b * BN + q * JP + tid];
        bool v = (t == t);
        st[tid] = v ? (_Float16)t : (_Float16)(-INFINITY);
        sp[tid] = v ? (_Float16)p : (_Float16)(-INFINITY);
        unsigned long long m = __ballot(v);
        if (tid == 0)
            __hip_atomic_fetch_add(&g_cnt[b], __popcll(m),
                                   __ATOMIC_RELAXED, __HIP_MEMORY_SCOPE_AGENT);
    }
    __syncthreads();

    // each thread owns 4 rows: i = r*256 + tid
    float tif[4];
    h8v ti8[4], pi8[4], acc8[4];
    #pragma unroll
    for (int r = 0; r < 4; ++r) {
        const int i = r * 256 + tid;
        float pf = P[b * BN + i];
        float tf = T[b * BN + i];
        tif[r] = tf;
        _Float16 th = (_Float16)tf;
        _Float16 ph = (_Float16)pf;
        ti8[r] = (h8v){th, th, th, th, th, th, th, th};
        pi8[r] = (h8v){ph, ph, ph, ph, ph, ph, ph, ph};
        acc8[r] = (h8v)0;
    }

    const h8v one8  = (h8v){1, 1, 1, 1, 1, 1, 1, 1};
    const h8v zero8 = (h8v)0;
    const u32x4 smask = (u32x4){0x80008000u, 0x80008000u, 0x80008000u, 0x80008000u};

    const h8v* sp8 = (const h8v*)sp;
    const h8v* st8 = (const h8v*)st;
    #pragma unroll
    for (int jj = 0; jj < JP / 8; ++jj) {
        const h8v t8 = st8[jj];   // broadcast ds_read_b128 (wave-uniform)
        const h8v p8 = sp8[jj];
        #pragma unroll
        for (int r = 0; r < 4; ++r) {
            h8v dt = t8 - ti8[r];                          // sign(tj - ti)
            u32x4 sb = __builtin_bit_cast(u32x4, dt) & smask;
            h8v d  = pi8[r] - p8;                          // pi - pj
            u32x4 sd = __builtin_bit_cast(u32x4, d) ^ sb;  // s * d
            h8v e  = __builtin_bit_cast(h8v, sd) + one8;   // 1 + s*d
            acc8[r] += __builtin_elementwise_max(e, zero8); // relu, accumulate
        }
    }

    float total = 0.0f;
    #pragma unroll
    for (int r = 0; r < 4; ++r) {
        const int i = r * 256 + tid;
        float s = 0.0f;
        #pragma unroll
        for (int k = 0; k < 8; ++k) s += (float)acc8[r][k];
        // diagonal j==i in this partition iff (i>>6)==q: term is exactly 1.0
        s -= ((i >> 6) == q) ? 1.0f : 0.0f;
        bool vi = (tif[r] == tif[r]);
        total += vi ? s : 0.0f;   // invalid rows (possibly inf acc) -> 0
    }

    // block reduction
    #pragma unroll
    for (int off = 32; off > 0; off >>= 1) total += __shfl_down(total, off);
    const int wid = tid >> 6, lane = tid & 63;
    if (lane == 0) wsum[wid] = total;
    __syncthreads();
    if (tid == 0) {
        float s = wsum[0] + wsum[1] + wsum[2] + wsum[3];
        __hip_atomic_fetch_add(&g_loss[b], s,
                               __ATOMIC_RELAXED, __HIP_MEMORY_SCOPE_AGENT);
        int old = __hip_atomic_fetch_add(&g_done, 1,
                                         __ATOMIC_ACQ_REL, __HIP_MEMORY_SCOPE_AGENT);
        s_last = (old == (NB * NPART - 1)) ? 1 : 0;
    }
    __syncthreads();
    if (!s_last) return;

    // ---- last block: finalize + reset globals for next call ----
    if (tid < NB) {
        float S = __hip_atomic_load(&g_loss[tid], __ATOMIC_ACQUIRE, __HIP_MEMORY_SCOPE_AGENT);
        int   n = __hip_atomic_load(&g_cnt[tid],  __ATOMIC_ACQUIRE, __HIP_MEMORY_SCOPE_AGENT);
        __hip_atomic_store(&g_loss[tid], 0.0f, __ATOMIC_RELAXED, __HIP_MEMORY_SCOPE_AGENT);
        __hip_atomic_store(&g_cnt[tid],  0,    __ATOMIC_RELAXED, __HIP_MEMORY_SCOPE_AGENT);
        float c  = (float)n * (float)(n - 1);
        float sl = S / fmaxf(c, 1.0f);
        float ok = (n > 1) ? 1.0f : 0.0f;
        float num = sl * ok;
        #pragma unroll
        for (int off = 32; off > 0; off >>= 1) {
            num += __shfl_down(num, off);
            ok  += __shfl_down(ok, off);
        }
        if (tid == 0) {
            out[0] = (ok > 0.0f) ? (num / ok) : 0.0f;
            __hip_atomic_store(&g_done, 0, __ATOMIC_RELEASE, __HIP_MEMORY_SCOPE_AGENT);
        }
    }
}

extern "C" void kernel_launch(void* const* d_in, const int* in_sizes, int n_in,
                              void* d_out, int out_size, void* d_ws, size_t ws_size,
                              hipStream_t stream) {
    const float* P = (const float*)d_in[0];   // predictions [64,1024] f32
    const float* T = (const float*)d_in[1];   // targets     [64,1024] f32 (NaNs)
    float* out = (float*)d_out;               // scalar f32

    prl_fused<<<NB * NPART, 256, 0, stream>>>(P, T, out);
}

// Round 4
// 66.488 us; speedup vs baseline: 1.1438x; 1.1438x over previous
//
#include <hip/hip_runtime.h>
#include <math.h>

// PairwiseRankingLoss: B=64, N=1024, margin=1.0
//   valid = ~isnan(targets); pairs (i,j), i!=j, both valid
//   loss_ij = relu(1 - (p_i - p_j)) if t_i > t_j else relu(1 + (p_i - p_j))
//           = relu(1 + ((p_i - p_j) XOR signbit(t_j - t_i)))   [branch-free]
//   sample_loss = sum_ij / max(n_valid*(n_valid-1), 1)
//   out = mean over samples with n_valid > 1 (0 if none)
//
// Structure (best measured, R2): 2 kernels, per-block result slots, NO atomics,
// NO memset. Inner loop in packed f16 (v_pk_*): 28 insts / 8 pairs (validated
// for accuracy in R3: passed, absmax 0).
// Invalid j staged as (t,p)=(-inf,-inf): for valid i, d=p_i+inf=+inf, sign(dt)=neg
// -> sd=-inf -> relu(1-inf)=0. Invalid rows masked at the end.

#define BN 1024
#define NB 64
#define NPART 16  // j-partitions per sample
#define JP 64     // j's per partition

typedef _Float16 h8v __attribute__((ext_vector_type(8)));
typedef unsigned int u32x4 __attribute__((ext_vector_type(4)));

// ---------------- Kernel A: pairwise partial sums + valid counts ----------------
// grid = NB*NPART blocks; block = 256 threads; thread owns 4 rows (i = tid+256r),
// loops the block's 64 staged j's from LDS (broadcast reads).
__global__ __launch_bounds__(256) void prl_pairs(const float* __restrict__ P,
                                                 const float* __restrict__ T,
                                                 float* __restrict__ ws_part,
                                                 int* __restrict__ ws_cnt) {
    const int blk = blockIdx.x;
    const int b   = blk >> 4;   // sample
    const int q   = blk & 15;   // j-partition
    const int tid = threadIdx.x;

    __shared__ __align__(16) _Float16 sp[JP];
    __shared__ __align__(16) _Float16 st[JP];

    if (tid < JP) {             // one wave stages + counts valids
        float t = T[b * BN + q * JP + tid];
        float p = P[b * BN + q * JP + tid];
        bool v = (t == t);
        st[tid] = v ? (_Float16)t : (_Float16)(-INFINITY);
        sp[tid] = v ? (_Float16)p : (_Float16)(-INFINITY);
        unsigned long long m = __ballot(v);
        if (tid == 0) ws_cnt[blk] = __popcll(m);
    }
    __syncthreads();

    float tif[4];
    h8v ti8[4], pi8[4], acc8[4];
    #pragma unroll
    for (int r = 0; r < 4; ++r) {
        const int i = r * 256 + tid;
        float pf = P[b * BN + i];
        float tf = T[b * BN + i];
        tif[r] = tf;
        _Float16 th = (_Float16)tf;
        _Float16 ph = (_Float16)pf;
        ti8[r] = (h8v){th, th, th, th, th, th, th, th};
        pi8[r] = (h8v){ph, ph, ph, ph, ph, ph, ph, ph};
        acc8[r] = (h8v)0;
    }

    const h8v one8  = (h8v){1, 1, 1, 1, 1, 1, 1, 1};
    const h8v zero8 = (h8v)0;
    const u32x4 smask = (u32x4){0x80008000u, 0x80008000u, 0x80008000u, 0x80008000u};

    const h8v* sp8 = (const h8v*)sp;
    const h8v* st8 = (const h8v*)st;
    #pragma unroll
    for (int jj = 0; jj < JP / 8; ++jj) {
        const h8v t8 = st8[jj];   // broadcast ds_read_b128 (wave-uniform addr)
        const h8v p8 = sp8[jj];
        #pragma unroll
        for (int r = 0; r < 4; ++r) {
            h8v dt = t8 - ti8[r];                           // tj - ti
            u32x4 sb = __builtin_bit_cast(u32x4, dt) & smask;
            h8v d  = pi8[r] - p8;                           // pi - pj
            u32x4 sd = __builtin_bit_cast(u32x4, d) ^ sb;   // s * d
            h8v e  = __builtin_bit_cast(h8v, sd) + one8;    // 1 + s*d
            acc8[r] += __builtin_elementwise_max(e, zero8); // relu, accumulate
        }
    }

    float total = 0.0f;
    #pragma unroll
    for (int r = 0; r < 4; ++r) {
        const int i = r * 256 + tid;
        float s = 0.0f;
        #pragma unroll
        for (int k = 0; k < 8; ++k) s += (float)acc8[r][k];
        // diagonal j==i lies in this partition iff (i>>6)==q; its term is
        // exactly relu(1+0)=1 (ti>ti false) -> remove it.
        s -= ((i >> 6) == q) ? 1.0f : 0.0f;
        bool vi = (tif[r] == tif[r]);
        total += vi ? s : 0.0f;   // invalid rows (inf/NaN acc) -> 0
    }

    // block reduction: wave shuffle then cross-wave LDS, one slot write
    #pragma unroll
    for (int off = 32; off > 0; off >>= 1) total += __shfl_down(total, off);
    __shared__ float wsum[4];
    const int wid = tid >> 6, lane = tid & 63;
    if (lane == 0) wsum[wid] = total;
    __syncthreads();
    if (tid == 0) ws_part[blk] = wsum[0] + wsum[1] + wsum[2] + wsum[3];
}

// ---------------- Kernel B: finalize (single wave) ----------------
__global__ __launch_bounds__(64) void prl_final(const float* __restrict__ ws_part,
                                                const int* __restrict__ ws_cnt,
                                                float* __restrict__ out) {
    const int s = threadIdx.x;   // sample 0..63
    float S = 0.0f;
    int   n = 0;
    #pragma unroll
    for (int k = 0; k < NPART; ++k) {
        S += ws_part[s * NPART + k];
        n += ws_cnt[s * NPART + k];
    }
    float c  = (float)n * (float)(n - 1);
    float sl = S / fmaxf(c, 1.0f);
    float ok = (n > 1) ? 1.0f : 0.0f;
    float num = sl * ok;
    #pragma unroll
    for (int off = 32; off > 0; off >>= 1) {
        num += __shfl_down(num, off);
        ok  += __shfl_down(ok, off);
    }
    if (s == 0) out[0] = (ok > 0.0f) ? (num / ok) : 0.0f;
}

extern "C" void kernel_launch(void* const* d_in, const int* in_sizes, int n_in,
                              void* d_out, int out_size, void* d_ws, size_t ws_size,
                              hipStream_t stream) {
    const float* P = (const float*)d_in[0];   // predictions [64,1024] f32
    const float* T = (const float*)d_in[1];   // targets     [64,1024] f32 (NaNs)
    float* out = (float*)d_out;               // scalar f32

    float* ws_part = (float*)d_ws;                  // [NB*NPART] partial sums
    int*   ws_cnt  = (int*)(ws_part + NB * NPART);  // [NB*NPART] valid counts
    // every slot written unconditionally -> no zero-init needed

    prl_pairs<<<NB * NPART, 256, 0, stream>>>(P, T, ws_part, ws_cnt);
    prl_final<<<1, 64, 0, stream>>>(ws_part, ws_cnt, out);
}